// Round 15
// baseline (350.310 us; speedup 1.0000x reference)
//
#include <hip/hip_runtime.h>
#include <math.h>

#define F_NODE 32
#define F_EDGE 8
#define HID 128

typedef __attribute__((ext_vector_type(2))) _Float16 f16x2;
typedef __attribute__((ext_vector_type(8))) _Float16 f16x8;
typedef __attribute__((ext_vector_type(4))) float f32x4;
typedef __attribute__((ext_vector_type(2))) float f32x2;

__device__ __forceinline__ float elu_f(float x) { return x > 0.f ? x : expf(x) - 1.f; }

__device__ __forceinline__ unsigned h2u(f16x2 h) { union { f16x2 h; unsigned u; } x; x.h = h; return x.u; }
__device__ __forceinline__ f16x2 u2h(unsigned u) { union { unsigned u; f16x2 h; } x; x.u = u; return x.h; }
__device__ __forceinline__ unsigned packh2(float lo, float hi) {
    f16x2 v; v.x = (_Float16)lo; v.y = (_Float16)hi; return h2u(v);
}
__device__ __forceinline__ unsigned short f2h_bits(float f) {
    _Float16 h = (_Float16)f; union { _Float16 h; unsigned short u; } x; x.h = h; return x.u;
}
__device__ __forceinline__ float hbits2f(unsigned short b) {
    union { unsigned short u; _Float16 h; } x; x.u = b; return (float)x.h;
}
__device__ __forceinline__ f16x8 frag_from(uint4 v) { union { uint4 u; f16x8 f; } x; x.u = v; return x.f; }
__device__ __forceinline__ f16x2 duph(f16x8 v, int k) { f16x2 d; d.x = v[k]; d.y = v[k]; return d; }

// ================= fused prep (grid-stride): casts + wpack + COARSE hist =================
__global__ __launch_bounds__(256) void prep_kernel(
    const float* __restrict__ x, const float* __restrict__ ea,
    const int* __restrict__ dst,
    uint4* __restrict__ xh4, uint4* __restrict__ eab4,
    const float* __restrict__ W1a, const float* __restrict__ W1b,
    const float* __restrict__ W2a, const float* __restrict__ W2b,
    const float* __restrict__ Wl1, const float* __restrict__ Wl2,
    uint4* __restrict__ P1a, uint4* __restrict__ P1b,
    uint4* __restrict__ P2a, uint4* __restrict__ P2b,
    uint4* __restrict__ P3a, uint4* __restrict__ P3b,
    int* __restrict__ cbkt, int nx, int ne2, int E, int NB)
{
    const int stride = gridDim.x * 256;
    const int tid = blockIdx.x * 256 + threadIdx.x;
    const float4* x4 = (const float4*)x;
    const float4* ea4 = (const float4*)ea;

    __shared__ int chist[512];
    for (int i = threadIdx.x; i < 512; i += 256) chist[i] = 0;
    __syncthreads();

    int nx4 = nx >> 2;
    for (int i = tid; i < nx4; i += stride) {
        float4 a = x4[i * 2], b = x4[i * 2 + 1];
        uint4 v;
        v.x = packh2(a.x, a.y);
        v.y = packh2(a.z, a.w);
        v.z = packh2(b.x, b.y);
        v.w = packh2(b.z, b.w);
        xh4[i] = v;
    }
    int ne8 = ne2 >> 2;
    for (int i = tid; i < ne8; i += stride) {
        float4 a = ea4[i * 2], b = ea4[i * 2 + 1];
        uint4 v;
        v.x = packh2(a.x, a.y);
        v.y = packh2(a.z, a.w);
        v.z = packh2(b.x, b.y);
        v.w = packh2(b.z, b.w);
        eab4[i] = v;
    }
    for (int f0 = tid; f0 < 8960; f0 += stride) {
        int f = f0;
        if (f >= 8704) {               // P3b: Wl2 [128][12] -> 16 cols padded
            f -= 8704;
            int lane = f & 63;
            int ks = f >> 6;
            int col = lane & 15;
            int k0 = ks * 32 + (lane >> 4) * 8;
            float w[8];
#pragma unroll
            for (int j = 0; j < 8; ++j) w[j] = col < 12 ? Wl2[(size_t)(k0 + j) * 12 + col] : 0.f;
            uint4 v;
            v.x = packh2(w[0], w[1]);
            v.y = packh2(w[2], w[3]);
            v.z = packh2(w[4], w[5]);
            v.w = packh2(w[6], w[7]);
            P3b[f] = v;
            continue;
        }
        const float* W; uint4* P; int KS;
        if (f < 512)       { W = W1a; P = P1a; KS = 1; }
        else if (f < 2560) { W = W1b; P = P1b; KS = 4; f -= 512; }
        else if (f < 4608) { W = W2a; P = P2a; KS = 4; f -= 2560; }
        else if (f < 6656) { W = W2b; P = P2b; KS = 4; f -= 4608; }
        else               { W = Wl1; P = P3a; KS = 4; f -= 6656; }
        int lane = f & 63;
        int rem = f >> 6;
        int ks = rem % KS, ct = rem / KS;
        int col = ct * 16 + (lane & 15);
        int k0 = ks * 32 + (lane >> 4) * 8;
        float w[8];
#pragma unroll
        for (int j = 0; j < 8; ++j) w[j] = W[(size_t)(k0 + j) * HID + col];
        uint4 v;
        v.x = packh2(w[0], w[1]);
        v.y = packh2(w[2], w[3]);
        v.z = packh2(w[4], w[5]);
        v.w = packh2(w[6], w[7]);
        P[f] = v;
    }
    int e4 = E >> 2;
    const int4* dst4 = (const int4*)dst;
    for (int i = tid; i < e4; i += stride) {
        int4 d = dst4[i];
        atomicAdd(&chist[d.x >> 8], 1);
        atomicAdd(&chist[d.y >> 8], 1);
        atomicAdd(&chist[d.z >> 8], 1);
        atomicAdd(&chist[d.w >> 8], 1);
    }
    for (int i = e4 * 4 + tid; i < E; i += stride)
        atomicAdd(&chist[dst[i] >> 8], 1);
    __syncthreads();
    for (int i = threadIdx.x; i < NB; i += 256) {
        int c = chist[i];
        if (c) atomicAdd(&cbkt[i], c);
    }
}

// ================= coarse bucket prefix (1 block, parallel scan) =================
__global__ __launch_bounds__(256) void scanB_kernel(const int* __restrict__ cbkt,
                             int* __restrict__ bucketOff, int* __restrict__ curB,
                             int NB, int E) {
    __shared__ int s[256];
    int t = threadIdx.x;
    int v0 = (2 * t     < NB) ? cbkt[2 * t]     : 0;
    int v1 = (2 * t + 1 < NB) ? cbkt[2 * t + 1] : 0;
    int tot = v0 + v1;
    s[t] = tot;
    __syncthreads();
    for (int o = 1; o < 256; o <<= 1) {
        int val = (t >= o) ? s[t - o] : 0;
        __syncthreads();
        s[t] += val;
        __syncthreads();
    }
    int excl = s[t] - tot;
    if (2 * t < NB)     { bucketOff[2 * t] = excl;          curB[2 * t] = excl; }
    if (2 * t + 1 < NB) { bucketOff[2 * t + 1] = excl + v0; curB[2 * t + 1] = excl + v0; }
    if (t == 0) bucketOff[NB] = E;
}

// ================= pass A: coarse bin into 256-node buckets =================
__global__ __launch_bounds__(256) void binA_kernel(
    const int* __restrict__ dst, const int* __restrict__ src,
    int* __restrict__ curB, int2* __restrict__ tmp, int E, int NB)
{
    __shared__ int hist[512];
    __shared__ int basev[512];
    const int tid = threadIdx.x;
    const int base = blockIdx.x * 4096;
    for (int i = tid; i < NB; i += 256) hist[i] = 0;
    __syncthreads();
    int d[16];
#pragma unroll
    for (int k = 0; k < 16; ++k) {
        int e = base + k * 256 + tid;
        d[k] = (e < E) ? dst[e] : -1;
        if (d[k] >= 0) atomicAdd(&hist[d[k] >> 8], 1);
    }
    __syncthreads();
    for (int i = tid; i < NB; i += 256) {
        int c = hist[i];
        basev[i] = c > 0 ? atomicAdd(&curB[i], c) : 0;
        hist[i] = 0;
    }
    __syncthreads();
#pragma unroll
    for (int k = 0; k < 16; ++k) {
        int e = base + k * 256 + tid;
        if (d[k] >= 0) {
            int b = d[k] >> 8;
            int r = atomicAdd(&hist[b], 1);
            tmp[basev[b] + r] = make_int2(e | ((d[k] & 255) << 22), src[e]);
        }
    }
}

// ================= pass B: per-node offsets in LDS + scatter + write off[] =====
__global__ __launch_bounds__(256) void binB_kernel(
    const int2* __restrict__ tmp, const int* __restrict__ bucketOff,
    const uint4* __restrict__ eab4,
    int* __restrict__ off, int* __restrict__ srcarr, uint4* __restrict__ easrt,
    int N, int E, int NB)
{
    __shared__ int hist[256];
    __shared__ int ss[256];
    const int b = blockIdx.x;
    const int tid = threadIdx.x;
    const int node0 = b << 8;
    const int base = bucketOff[b];
    const int end = bucketOff[b + 1];
    const int S = end - base;

    hist[tid] = 0;
    __syncthreads();
    for (int j = tid; j < S; j += 256) {
        int2 rec = tmp[base + j];
        atomicAdd(&hist[((unsigned)rec.x) >> 22], 1);
    }
    __syncthreads();
    int v = hist[tid];
    ss[tid] = v;
    __syncthreads();
    for (int o = 1; o < 256; o <<= 1) {
        int val = (tid >= o) ? ss[tid - o] : 0;
        __syncthreads();
        ss[tid] += val;
        __syncthreads();
    }
    int excl = ss[tid] - v;
    int node = node0 + tid;
    if (node < N) off[node] = base + excl;
    if (b == NB - 1 && tid == 0) off[N] = E;
    hist[tid] = excl;     // reuse as cursor
    __syncthreads();
    for (int j = tid; j < S; j += 256) {
        int2 rec = tmp[base + j];
        int dloc = ((unsigned)rec.x) >> 22;
        int slot = base + atomicAdd(&hist[dloc], 1);
        srcarr[slot] = rec.y;
        easrt[slot] = eab4[rec.x & 0x3FFFFF];   // one-time random ea gather
    }
}

// ================= conv1 gather-aggregate (f16 gathers, sequential ea) =================
__global__ __launch_bounds__(256) void agg1_kernel(
    const float* __restrict__ x, const unsigned* __restrict__ xh,
    const uint4* __restrict__ easrt,
    const float* __restrict__ We, const float* __restrict__ be,
    const int* __restrict__ off, const int* __restrict__ srcarr,
    unsigned* __restrict__ aggh, int N)
{
    int wave = (blockIdx.x * 256 + threadIdx.x) >> 6;
    if (wave >= N) return;
    int lane = threadIdx.x & 63;
    int fp = lane & 15, eg = lane >> 4;
    int j0 = fp * 2;
    f16x2 w2[F_EDGE];
#pragma unroll
    for (int k = 0; k < F_EDGE; ++k)
        w2[k] = u2h(packh2(We[k * F_NODE + j0], We[k * F_NODE + j0 + 1]));
    f16x2 bias2 = u2h(packh2(be[j0], be[j0 + 1]));
    f16x2 zero2 = u2h(0u);
    int i0 = __builtin_amdgcn_readfirstlane(off[wave]);
    int i1 = __builtin_amdgcn_readfirstlane(off[wave + 1]);
    float acc0 = 0.f, acc1 = 0.f;
    for (int i = i0; i < i1; i += 4) {
        int ii = i + eg;
        if (ii < i1) {
            int s = srcarr[ii];
            f16x8 ev = frag_from(easrt[ii]);
            f16x2 m = bias2 + u2h(xh[(size_t)s * 16 + fp]);
#pragma unroll
            for (int k = 0; k < F_EDGE; ++k)
                m = duph(ev, k) * w2[k] + m;
            m = __builtin_elementwise_max(m, zero2);
            acc0 += (float)m.x;
            acc1 += (float)m.y;
        }
    }
    acc0 += __shfl_xor(acc0, 16, 64);
    acc0 += __shfl_xor(acc0, 32, 64);
    acc1 += __shfl_xor(acc1, 16, 64);
    acc1 += __shfl_xor(acc1, 32, 64);
    if (eg == 0) {
        float2 xo = *(const float2*)&x[(size_t)wave * F_NODE + j0];
        aggh[(size_t)wave * 16 + fp] = packh2(xo.x + acc0, xo.y + acc1);
    }
}

// ================= conv2 gather-aggregate (fp8, half-wave edge split) =================
// lanes 0-31 process even edges, 32-63 odd edges; each lane owns a 4-feature
// quad (one dword of fp8) -> one global_load_dword serves 2 edges' 128B rows.
__global__ __launch_bounds__(256) void agg2_kernel(
    const unsigned* __restrict__ hh, const unsigned* __restrict__ h8u,
    const uint4* __restrict__ easrt,
    const float* __restrict__ We, const float* __restrict__ be,
    const int* __restrict__ off, const int* __restrict__ srcarr,
    unsigned* __restrict__ aggh, int N)
{
    int wave = (blockIdx.x * 256 + threadIdx.x) >> 6;
    if (wave >= N) return;
    int lane = threadIdx.x & 63;
    int half = lane >> 5;
    int fl = lane & 31;
    int j0 = fl * 4;
    f16x2 wA[F_EDGE], wB[F_EDGE];
#pragma unroll
    for (int k = 0; k < F_EDGE; ++k) {
        wA[k] = u2h(packh2(We[k * HID + j0],     We[k * HID + j0 + 1]));
        wB[k] = u2h(packh2(We[k * HID + j0 + 2], We[k * HID + j0 + 3]));
    }
    f16x2 biasA = u2h(packh2(be[j0], be[j0 + 1]));
    f16x2 biasB = u2h(packh2(be[j0 + 2], be[j0 + 3]));
    f16x2 zero2 = u2h(0u);
    int i0 = __builtin_amdgcn_readfirstlane(off[wave]);
    int i1 = __builtin_amdgcn_readfirstlane(off[wave + 1]);
    float acc0 = 0.f, acc1 = 0.f, acc2 = 0.f, acc3 = 0.f;
    int base = i0;
    for (; base + 8 <= i1; base += 8) {
        int e[4], s[4];
        unsigned u[4];
        f16x8 ev[4];
#pragma unroll
        for (int k = 0; k < 4; ++k) e[k] = base + 2 * k + half;
#pragma unroll
        for (int k = 0; k < 4; ++k) s[k] = srcarr[e[k]];
#pragma unroll
        for (int k = 0; k < 4; ++k) u[k] = h8u[(size_t)s[k] * 32 + fl];
#pragma unroll
        for (int k = 0; k < 4; ++k) ev[k] = frag_from(easrt[e[k]]);
#pragma unroll
        for (int k = 0; k < 4; ++k) {
            f32x2 flo = __builtin_amdgcn_cvt_pk_f32_fp8((int)u[k], false);
            f32x2 fhi = __builtin_amdgcn_cvt_pk_f32_fp8((int)u[k], true);
            f16x2 mA; mA.x = (_Float16)flo.x; mA.y = (_Float16)flo.y; mA = biasA + mA;
            f16x2 mB; mB.x = (_Float16)fhi.x; mB.y = (_Float16)fhi.y; mB = biasB + mB;
#pragma unroll
            for (int kk = 0; kk < F_EDGE; ++kk) {
                f16x2 c = duph(ev[k], kk);
                mA = c * wA[kk] + mA;
                mB = c * wB[kk] + mB;
            }
            mA = __builtin_elementwise_max(mA, zero2);
            mB = __builtin_elementwise_max(mB, zero2);
            acc0 += (float)mA.x;
            acc1 += (float)mA.y;
            acc2 += (float)mB.x;
            acc3 += (float)mB.y;
        }
    }
    for (int e = base + half; e < i1; e += 2) {
        int s0 = srcarr[e];
        unsigned u0 = h8u[(size_t)s0 * 32 + fl];
        f16x8 ev = frag_from(easrt[e]);
        f32x2 flo = __builtin_amdgcn_cvt_pk_f32_fp8((int)u0, false);
        f32x2 fhi = __builtin_amdgcn_cvt_pk_f32_fp8((int)u0, true);
        f16x2 mA; mA.x = (_Float16)flo.x; mA.y = (_Float16)flo.y; mA = biasA + mA;
        f16x2 mB; mB.x = (_Float16)fhi.x; mB.y = (_Float16)fhi.y; mB = biasB + mB;
#pragma unroll
        for (int kk = 0; kk < F_EDGE; ++kk) {
            f16x2 c = duph(ev, kk);
            mA = c * wA[kk] + mA;
            mB = c * wB[kk] + mB;
        }
        mA = __builtin_elementwise_max(mA, zero2);
        mB = __builtin_elementwise_max(mB, zero2);
        acc0 += (float)mA.x;
        acc1 += (float)mA.y;
        acc2 += (float)mB.x;
        acc3 += (float)mB.y;
    }
    acc0 += __shfl_xor(acc0, 32, 64);
    acc1 += __shfl_xor(acc1, 32, 64);
    acc2 += __shfl_xor(acc2, 32, 64);
    acc3 += __shfl_xor(acc3, 32, 64);
    if (half == 0) {
        f16x2 s0 = u2h(hh[(size_t)wave * 64 + fl * 2]);
        f16x2 s1 = u2h(hh[(size_t)wave * 64 + fl * 2 + 1]);
        uint2 outv;
        outv.x = packh2((float)s0.x + acc0, (float)s0.y + acc1);
        outv.y = packh2((float)s1.x + acc2, (float)s1.y + acc3);
        *(uint2*)&aggh[(size_t)wave * 64 + fl * 2] = outv;
    }
}

// ================= fused 2-layer node MLP via f16 MFMA =================
__device__ __forceinline__ void put_tile_elu_h(unsigned short* t, f32x4 v, int rbase, int c, int stride) {
#pragma unroll
    for (int j = 0; j < 4; ++j)
        t[(rbase + j) * stride + c] = f2h_bits(elu_f(v[j]));
}
__device__ __forceinline__ void put_tile_relu_h(unsigned short* t, f32x4 v, int rbase, int c, int stride) {
#pragma unroll
    for (int j = 0; j < 4; ++j)
        t[(rbase + j) * stride + c] = f2h_bits(fmaxf(v[j], 0.f));
}

template <int K, bool POOL, bool DUP8>
__global__ __launch_bounds__(256) void mlp_mfma_kernel(
    const uint4* __restrict__ inb,
    const uint4* __restrict__ WaP, const float* __restrict__ ba,
    const uint4* __restrict__ WbP, const float* __restrict__ bb,
    uint4* __restrict__ outb, unsigned* __restrict__ out8,
    const int* __restrict__ batch, float* __restrict__ hg,
    int nrows)
{
    constexpr int KS_A = K / 32;
    constexpr int SA = K + 8;
    constexpr int ST = HID + 8;
    constexpr int STF = HID + 4;
    __shared__ __align__(16) unsigned short a_s[32 * SA];
    __shared__ __align__(16) unsigned short t_s[32 * ST];
    __shared__ float p_s[POOL ? 32 * STF : 1];
    __shared__ int batch_s[POOL ? 32 : 1];

    const int tid = threadIdx.x;
    const int row0 = blockIdx.x * 32;

    constexpr int Q = K / 8;
    for (int idx = tid; idx < 32 * Q; idx += 256) {
        int r = idx / Q, q = idx % Q;
        uint4 v = make_uint4(0, 0, 0, 0);
        if (row0 + r < nrows) v = inb[(size_t)(row0 + r) * Q + q];
        *(uint4*)&a_s[r * SA + q * 8] = v;
    }
    if (POOL && tid < 32)
        batch_s[tid] = (row0 + tid < nrows) ? batch[row0 + tid] : -1;
    __syncthreads();

    const int lane = tid & 63;
    const int w = tid >> 6;
    const int rb = w >> 1;
    const int cg = (w & 1) * 4;
    const int cf = lane & 15;
    const int g = lane >> 4;
    const int arow = rb * 16 + cf;

    f32x4 acc0, acc1, acc2, acc3;
    {
        float c0 = ba[(cg + 0) * 16 + cf], c1 = ba[(cg + 1) * 16 + cf];
        float c2 = ba[(cg + 2) * 16 + cf], c3 = ba[(cg + 3) * 16 + cf];
        acc0 = (f32x4){c0, c0, c0, c0};
        acc1 = (f32x4){c1, c1, c1, c1};
        acc2 = (f32x4){c2, c2, c2, c2};
        acc3 = (f32x4){c3, c3, c3, c3};
    }
#pragma unroll
    for (int ks = 0; ks < KS_A; ++ks) {
        f16x8 a = *(const f16x8*)&a_s[arow * SA + ks * 32 + g * 8];
        acc0 = __builtin_amdgcn_mfma_f32_16x16x32_f16(a, frag_from(WaP[((cg + 0) * KS_A + ks) * 64 + lane]), acc0, 0, 0, 0);
        acc1 = __builtin_amdgcn_mfma_f32_16x16x32_f16(a, frag_from(WaP[((cg + 1) * KS_A + ks) * 64 + lane]), acc1, 0, 0, 0);
        acc2 = __builtin_amdgcn_mfma_f32_16x16x32_f16(a, frag_from(WaP[((cg + 2) * KS_A + ks) * 64 + lane]), acc2, 0, 0, 0);
        acc3 = __builtin_amdgcn_mfma_f32_16x16x32_f16(a, frag_from(WaP[((cg + 3) * KS_A + ks) * 64 + lane]), acc3, 0, 0, 0);
    }
    {
        int rbase = rb * 16 + g * 4;
        put_tile_elu_h(t_s, acc0, rbase, (cg + 0) * 16 + cf, ST);
        put_tile_elu_h(t_s, acc1, rbase, (cg + 1) * 16 + cf, ST);
        put_tile_elu_h(t_s, acc2, rbase, (cg + 2) * 16 + cf, ST);
        put_tile_elu_h(t_s, acc3, rbase, (cg + 3) * 16 + cf, ST);
    }
    __syncthreads();

    {
        float c0 = bb[(cg + 0) * 16 + cf], c1 = bb[(cg + 1) * 16 + cf];
        float c2 = bb[(cg + 2) * 16 + cf], c3 = bb[(cg + 3) * 16 + cf];
        acc0 = (f32x4){c0, c0, c0, c0};
        acc1 = (f32x4){c1, c1, c1, c1};
        acc2 = (f32x4){c2, c2, c2, c2};
        acc3 = (f32x4){c3, c3, c3, c3};
    }
#pragma unroll
    for (int ks = 0; ks < 4; ++ks) {
        f16x8 a = *(const f16x8*)&t_s[arow * ST + ks * 32 + g * 8];
        acc0 = __builtin_amdgcn_mfma_f32_16x16x32_f16(a, frag_from(WbP[((cg + 0) * 4 + ks) * 64 + lane]), acc0, 0, 0, 0);
        acc1 = __builtin_amdgcn_mfma_f32_16x16x32_f16(a, frag_from(WbP[((cg + 1) * 4 + ks) * 64 + lane]), acc1, 0, 0, 0);
        acc2 = __builtin_amdgcn_mfma_f32_16x16x32_f16(a, frag_from(WbP[((cg + 2) * 4 + ks) * 64 + lane]), acc2, 0, 0, 0);
        acc3 = __builtin_amdgcn_mfma_f32_16x16x32_f16(a, frag_from(WbP[((cg + 3) * 4 + ks) * 64 + lane]), acc3, 0, 0, 0);
    }

    if (POOL) {
        int rbase = rb * 16 + g * 4;
#pragma unroll
        for (int j = 0; j < 4; ++j) {
            p_s[(rbase + j) * STF + (cg + 0) * 16 + cf] = elu_f(acc0[j]);
            p_s[(rbase + j) * STF + (cg + 1) * 16 + cf] = elu_f(acc1[j]);
            p_s[(rbase + j) * STF + (cg + 2) * 16 + cf] = elu_f(acc2[j]);
            p_s[(rbase + j) * STF + (cg + 3) * 16 + cf] = elu_f(acc3[j]);
        }
        __syncthreads();
        int f = tid & 127, grp = tid >> 7;
        float acc = 0.f;
        int cur = -1;
#pragma unroll 4
        for (int r = 0; r < 16; ++r) {
            int rr = grp * 16 + r;
            int b = batch_s[rr];
            if (b >= 0) {
                if (b != cur) {
                    if (cur >= 0) atomicAdd(&hg[(size_t)cur * HID + f], acc);
                    acc = 0.f;
                    cur = b;
                }
                acc += p_s[rr * STF + f];
            }
        }
        if (cur >= 0) atomicAdd(&hg[(size_t)cur * HID + f], acc);
    } else {
        __syncthreads();
        int rbase = rb * 16 + g * 4;
        put_tile_elu_h(t_s, acc0, rbase, (cg + 0) * 16 + cf, ST);
        put_tile_elu_h(t_s, acc1, rbase, (cg + 1) * 16 + cf, ST);
        put_tile_elu_h(t_s, acc2, rbase, (cg + 2) * 16 + cf, ST);
        put_tile_elu_h(t_s, acc3, rbase, (cg + 3) * 16 + cf, ST);
        __syncthreads();
        for (int idx = tid; idx < 32 * 16; idx += 256) {
            int r = idx >> 4, q = idx & 15;
            if (row0 + r < nrows)
                outb[(size_t)(row0 + r) * 16 + q] = *(const uint4*)&t_s[r * ST + q * 8];
        }
        if (DUP8) {
            for (int idx = tid; idx < 32 * 32; idx += 256) {
                int r = idx >> 5, q = idx & 31;
                if (row0 + r < nrows) {
                    float f0 = hbits2f(t_s[r * ST + q * 4 + 0]);
                    float f1 = hbits2f(t_s[r * ST + q * 4 + 1]);
                    float f2 = hbits2f(t_s[r * ST + q * 4 + 2]);
                    float f3 = hbits2f(t_s[r * ST + q * 4 + 3]);
                    int u = __builtin_amdgcn_cvt_pk_fp8_f32(f0, f1, 0, false);
                    u = __builtin_amdgcn_cvt_pk_fp8_f32(f2, f3, u, true);
                    out8[(size_t)(row0 + r) * 32 + q] = (unsigned)u;
                }
            }
        }
    }
}

// ================= head via MFMA =================
__global__ __launch_bounds__(256) void head_mfma_kernel(
    const float* __restrict__ hg,
    const uint4* __restrict__ Wl1P, const float* __restrict__ bl1,
    const uint4* __restrict__ Wl2P, const float* __restrict__ bl2,
    float* __restrict__ out, int G)
{
    constexpr int ST = HID + 8;
    __shared__ __align__(16) unsigned short a_s[32 * ST];
    __shared__ __align__(16) unsigned short t_s[32 * ST];

    const int tid = threadIdx.x;
    const int row0 = blockIdx.x * 32;

    for (int idx = tid; idx < 32 * HID; idx += 256) {
        int r = idx >> 7, c = idx & 127;
        float v = (row0 + r < G) ? hg[(size_t)(row0 + r) * HID + c] : 0.f;
        a_s[r * ST + c] = f2h_bits(v);
    }
    __syncthreads();

    const int lane = tid & 63;
    const int w = tid >> 6;
    const int rb = w >> 1;
    const int cg = (w & 1) * 4;
    const int cf = lane & 15;
    const int g = lane >> 4;
    const int arow = rb * 16 + cf;

    f32x4 acc0, acc1, acc2, acc3;
    {
        float c0 = bl1[(cg + 0) * 16 + cf], c1 = bl1[(cg + 1) * 16 + cf];
        float c2 = bl1[(cg + 2) * 16 + cf], c3 = bl1[(cg + 3) * 16 + cf];
        acc0 = (f32x4){c0, c0, c0, c0};
        acc1 = (f32x4){c1, c1, c1, c1};
        acc2 = (f32x4){c2, c2, c2, c2};
        acc3 = (f32x4){c3, c3, c3, c3};
    }
#pragma unroll
    for (int ks = 0; ks < 4; ++ks) {
        f16x8 a = *(const f16x8*)&a_s[arow * ST + ks * 32 + g * 8];
        acc0 = __builtin_amdgcn_mfma_f32_16x16x32_f16(a, frag_from(Wl1P[((cg + 0) * 4 + ks) * 64 + lane]), acc0, 0, 0, 0);
        acc1 = __builtin_amdgcn_mfma_f32_16x16x32_f16(a, frag_from(Wl1P[((cg + 1) * 4 + ks) * 64 + lane]), acc1, 0, 0, 0);
        acc2 = __builtin_amdgcn_mfma_f32_16x16x32_f16(a, frag_from(Wl1P[((cg + 2) * 4 + ks) * 64 + lane]), acc2, 0, 0, 0);
        acc3 = __builtin_amdgcn_mfma_f32_16x16x32_f16(a, frag_from(Wl1P[((cg + 3) * 4 + ks) * 64 + lane]), acc3, 0, 0, 0);
    }
    {
        int rbase = rb * 16 + g * 4;
        put_tile_relu_h(t_s, acc0, rbase, (cg + 0) * 16 + cf, ST);
        put_tile_relu_h(t_s, acc1, rbase, (cg + 1) * 16 + cf, ST);
        put_tile_relu_h(t_s, acc2, rbase, (cg + 2) * 16 + cf, ST);
        put_tile_relu_h(t_s, acc3, rbase, (cg + 3) * 16 + cf, ST);
    }
    __syncthreads();

    if ((w & 1) == 0) {
        float c0 = cf < 12 ? bl2[cf] : 0.f;
        f32x4 acc = (f32x4){c0, c0, c0, c0};
#pragma unroll
        for (int ks = 0; ks < 4; ++ks) {
            f16x8 a = *(const f16x8*)&t_s[arow * ST + ks * 32 + g * 8];
            acc = __builtin_amdgcn_mfma_f32_16x16x32_f16(a, frag_from(Wl2P[ks * 64 + lane]), acc, 0, 0, 0);
        }
        if (cf < 12) {
            int rbase = rb * 16 + g * 4;
#pragma unroll
            for (int j = 0; j < 4; ++j) {
                int row = row0 + rbase + j;
                if (row < G) out[(size_t)row * 12 + cf] = acc[j];
            }
        }
    }
}

extern "C" void kernel_launch(void* const* d_in, const int* in_sizes, int n_in,
                              void* d_out, int out_size, void* d_ws, size_t ws_size,
                              hipStream_t stream)
{
    const float* x    = (const float*)d_in[0];
    const int*   ei   = (const int*)d_in[1];
    const float* ea   = (const float*)d_in[2];
    const int*   batch = (const int*)d_in[3];
    const float* We1 = (const float*)d_in[4];
    const float* be1 = (const float*)d_in[5];
    const float* W1a = (const float*)d_in[6];
    const float* b1a = (const float*)d_in[7];
    const float* W1b = (const float*)d_in[8];
    const float* b1b = (const float*)d_in[9];
    const float* We2 = (const float*)d_in[10];
    const float* be2 = (const float*)d_in[11];
    const float* W2a = (const float*)d_in[12];
    const float* b2a = (const float*)d_in[13];
    const float* W2b = (const float*)d_in[14];
    const float* b2b = (const float*)d_in[15];
    const float* Wl1 = (const float*)d_in[16];
    const float* bl1 = (const float*)d_in[17];
    const float* Wl2 = (const float*)d_in[18];
    const float* bl2 = (const float*)d_in[19];
    float* out = (float*)d_out;

    const int N = in_sizes[0] / F_NODE;
    const int E = in_sizes[1] / 2;
    const int G = out_size / 12;
    const int NB = (N + 255) >> 8;

    const int* srcp = ei;
    const int* dstp = ei + E;

    // ---- workspace layout (lifetime-based aliasing) ----
    char* wsb = (char*)d_ws;
    auto alloc = [&](size_t bytes) -> char* {
        char* p = wsb;
        wsb += (bytes + 15) & ~(size_t)15;
        return p;
    };
    int* cbkt      = (int*)alloc(512 * 4);
    int* bucketOff = (int*)alloc(513 * 4);
    int* curB      = (int*)alloc(512 * 4);
    int* off       = (int*)alloc((size_t)(N + 1) * 4);
    int2* tmp      = (int2*)alloc((size_t)E * 8);          // dead after binB -> reused as h8
    unsigned short* h8 = (unsigned short*)tmp;             // N*128 fp8 bytes <= E*8
    int* srcarr    = (int*)alloc((size_t)E * 4);
    uint4* easrt   = (uint4*)alloc((size_t)E * 16);
    unsigned* xh   = (unsigned*)alloc((size_t)N * 16 * 4);
    unsigned* eab  = (unsigned*)alloc((size_t)E * 4 * 4);  // dead after binB -> reused as agg2h
    unsigned* agg2h = eab;
    unsigned* agg1h = (unsigned*)alloc((size_t)N * 16 * 4);
    unsigned* h1h   = (unsigned*)alloc((size_t)N * 64 * 4);
    float* hg  = (float*)alloc((size_t)G * HID * 4);
    uint4* P1a = (uint4*)alloc(512 * 16);
    uint4* P1b = (uint4*)alloc(2048 * 16);
    uint4* P2a = (uint4*)alloc(2048 * 16);
    uint4* P2b = (uint4*)alloc(2048 * 16);
    uint4* P3a = (uint4*)alloc(2048 * 16);
    uint4* P3b = (uint4*)alloc(256 * 16);

    (void)hipMemsetAsync(cbkt, 0, 512 * sizeof(int), stream);
    (void)hipMemsetAsync(hg, 0, (size_t)G * HID * sizeof(float), stream);

    // ---- prep: casts + wpack + coarse hist ----
    hipLaunchKernelGGL(prep_kernel, dim3(2048), dim3(256), 0, stream,
                       x, ea, dstp, (uint4*)xh, (uint4*)eab, W1a, W1b, W2a, W2b, Wl1, Wl2,
                       P1a, P1b, P2a, P2b, P3a, P3b, cbkt, N * 16, E * 4, E, NB);
    hipLaunchKernelGGL(scanB_kernel, dim3(1), dim3(256), 0, stream, cbkt, bucketOff, curB, NB, E);
    hipLaunchKernelGGL(binA_kernel, dim3((E + 4095) / 4096), dim3(256), 0, stream,
                       dstp, srcp, curB, tmp, E, NB);
    hipLaunchKernelGGL(binB_kernel, dim3(NB), dim3(256), 0, stream,
                       tmp, bucketOff, (const uint4*)eab, off, srcarr, easrt, N, E, NB);

    // ---- conv1 ----
    hipLaunchKernelGGL(agg1_kernel, dim3((N + 3) / 4), dim3(256), 0, stream,
                       x, xh, easrt, We1, be1, off, srcarr, agg1h, N);
    hipLaunchKernelGGL((mlp_mfma_kernel<F_NODE, false, true>), dim3((N + 31) / 32), dim3(256), 0, stream,
                       (const uint4*)agg1h, P1a, b1a, P1b, b1b, (uint4*)h1h, (unsigned*)h8,
                       (const int*)nullptr, (float*)nullptr, N);

    // ---- conv2 ----
    hipLaunchKernelGGL(agg2_kernel, dim3((N + 3) / 4), dim3(256), 0, stream,
                       h1h, (const unsigned*)h8, easrt, We2, be2, off, srcarr, agg2h, N);
    hipLaunchKernelGGL((mlp_mfma_kernel<HID, true, false>), dim3((N + 31) / 32), dim3(256), 0, stream,
                       (const uint4*)agg2h, P2a, b2a, P2b, b2b, (uint4*)nullptr, (unsigned*)nullptr,
                       batch, hg, N);

    // ---- head (MFMA) ----
    hipLaunchKernelGGL(head_mfma_kernel, dim3((G + 31) / 32), dim3(256), 0, stream,
                       hg, P3a, bl1, P3b, bl2, out, G);
}

// Round 16
// 339.822 us; speedup vs baseline: 1.0309x; 1.0309x over previous
//
#include <hip/hip_runtime.h>
#include <math.h>

#define F_NODE 32
#define F_EDGE 8
#define HID 128

typedef __attribute__((ext_vector_type(2))) _Float16 f16x2;
typedef __attribute__((ext_vector_type(8))) _Float16 f16x8;
typedef __attribute__((ext_vector_type(4))) float f32x4;
typedef __attribute__((ext_vector_type(2))) float f32x2;

__device__ __forceinline__ float elu_f(float x) { return x > 0.f ? x : expf(x) - 1.f; }

__device__ __forceinline__ unsigned h2u(f16x2 h) { union { f16x2 h; unsigned u; } x; x.h = h; return x.u; }
__device__ __forceinline__ f16x2 u2h(unsigned u) { union { unsigned u; f16x2 h; } x; x.u = u; return x.h; }
__device__ __forceinline__ unsigned packh2(float lo, float hi) {
    f16x2 v; v.x = (_Float16)lo; v.y = (_Float16)hi; return h2u(v);
}
__device__ __forceinline__ unsigned short f2h_bits(float f) {
    _Float16 h = (_Float16)f; union { _Float16 h; unsigned short u; } x; x.h = h; return x.u;
}
__device__ __forceinline__ float hbits2f(unsigned short b) {
    union { unsigned short u; _Float16 h; } x; x.u = b; return (float)x.h;
}
__device__ __forceinline__ f16x8 frag_from(uint4 v) { union { uint4 u; f16x8 f; } x; x.u = v; return x.f; }
__device__ __forceinline__ f16x2 duph(f16x8 v, int k) { f16x2 d; d.x = v[k]; d.y = v[k]; return d; }

// ================= fused prep (grid-stride): casts + wpack + COARSE hist =================
__global__ __launch_bounds__(256) void prep_kernel(
    const float* __restrict__ x, const float* __restrict__ ea,
    const int* __restrict__ dst,
    uint4* __restrict__ xh4, uint4* __restrict__ eab4,
    const float* __restrict__ W1a, const float* __restrict__ W1b,
    const float* __restrict__ W2a, const float* __restrict__ W2b,
    const float* __restrict__ Wl1, const float* __restrict__ Wl2,
    uint4* __restrict__ P1a, uint4* __restrict__ P1b,
    uint4* __restrict__ P2a, uint4* __restrict__ P2b,
    uint4* __restrict__ P3a, uint4* __restrict__ P3b,
    int* __restrict__ cbkt, int nx, int ne2, int E, int NB)
{
    const int stride = gridDim.x * 256;
    const int tid = blockIdx.x * 256 + threadIdx.x;
    const float4* x4 = (const float4*)x;
    const float4* ea4 = (const float4*)ea;

    __shared__ int chist[512];
    for (int i = threadIdx.x; i < 512; i += 256) chist[i] = 0;
    __syncthreads();

    int nx4 = nx >> 2;
    for (int i = tid; i < nx4; i += stride) {
        float4 a = x4[i * 2], b = x4[i * 2 + 1];
        uint4 v;
        v.x = packh2(a.x, a.y);
        v.y = packh2(a.z, a.w);
        v.z = packh2(b.x, b.y);
        v.w = packh2(b.z, b.w);
        xh4[i] = v;
    }
    int ne8 = ne2 >> 2;
    for (int i = tid; i < ne8; i += stride) {
        float4 a = ea4[i * 2], b = ea4[i * 2 + 1];
        uint4 v;
        v.x = packh2(a.x, a.y);
        v.y = packh2(a.z, a.w);
        v.z = packh2(b.x, b.y);
        v.w = packh2(b.z, b.w);
        eab4[i] = v;
    }
    for (int f0 = tid; f0 < 8960; f0 += stride) {
        int f = f0;
        if (f >= 8704) {               // P3b: Wl2 [128][12] -> 16 cols padded
            f -= 8704;
            int lane = f & 63;
            int ks = f >> 6;
            int col = lane & 15;
            int k0 = ks * 32 + (lane >> 4) * 8;
            float w[8];
#pragma unroll
            for (int j = 0; j < 8; ++j) w[j] = col < 12 ? Wl2[(size_t)(k0 + j) * 12 + col] : 0.f;
            uint4 v;
            v.x = packh2(w[0], w[1]);
            v.y = packh2(w[2], w[3]);
            v.z = packh2(w[4], w[5]);
            v.w = packh2(w[6], w[7]);
            P3b[f] = v;
            continue;
        }
        const float* W; uint4* P; int KS;
        if (f < 512)       { W = W1a; P = P1a; KS = 1; }
        else if (f < 2560) { W = W1b; P = P1b; KS = 4; f -= 512; }
        else if (f < 4608) { W = W2a; P = P2a; KS = 4; f -= 2560; }
        else if (f < 6656) { W = W2b; P = P2b; KS = 4; f -= 4608; }
        else               { W = Wl1; P = P3a; KS = 4; f -= 6656; }
        int lane = f & 63;
        int rem = f >> 6;
        int ks = rem % KS, ct = rem / KS;
        int col = ct * 16 + (lane & 15);
        int k0 = ks * 32 + (lane >> 4) * 8;
        float w[8];
#pragma unroll
        for (int j = 0; j < 8; ++j) w[j] = W[(size_t)(k0 + j) * HID + col];
        uint4 v;
        v.x = packh2(w[0], w[1]);
        v.y = packh2(w[2], w[3]);
        v.z = packh2(w[4], w[5]);
        v.w = packh2(w[6], w[7]);
        P[f] = v;
    }
    int e4 = E >> 2;
    const int4* dst4 = (const int4*)dst;
    for (int i = tid; i < e4; i += stride) {
        int4 d = dst4[i];
        atomicAdd(&chist[d.x >> 8], 1);
        atomicAdd(&chist[d.y >> 8], 1);
        atomicAdd(&chist[d.z >> 8], 1);
        atomicAdd(&chist[d.w >> 8], 1);
    }
    for (int i = e4 * 4 + tid; i < E; i += stride)
        atomicAdd(&chist[dst[i] >> 8], 1);
    __syncthreads();
    for (int i = threadIdx.x; i < NB; i += 256) {
        int c = chist[i];
        if (c) atomicAdd(&cbkt[i], c);
    }
}

// ================= coarse bucket prefix (1 block, parallel scan) =================
__global__ __launch_bounds__(256) void scanB_kernel(const int* __restrict__ cbkt,
                             int* __restrict__ bucketOff, int* __restrict__ curB,
                             int NB, int E) {
    __shared__ int s[256];
    int t = threadIdx.x;
    int v0 = (2 * t     < NB) ? cbkt[2 * t]     : 0;
    int v1 = (2 * t + 1 < NB) ? cbkt[2 * t + 1] : 0;
    int tot = v0 + v1;
    s[t] = tot;
    __syncthreads();
    for (int o = 1; o < 256; o <<= 1) {
        int val = (t >= o) ? s[t - o] : 0;
        __syncthreads();
        s[t] += val;
        __syncthreads();
    }
    int excl = s[t] - tot;
    if (2 * t < NB)     { bucketOff[2 * t] = excl;          curB[2 * t] = excl; }
    if (2 * t + 1 < NB) { bucketOff[2 * t + 1] = excl + v0; curB[2 * t + 1] = excl + v0; }
    if (t == 0) bucketOff[NB] = E;
}

// ================= pass A: coarse bin into 256-node buckets =================
__global__ __launch_bounds__(256) void binA_kernel(
    const int* __restrict__ dst, const int* __restrict__ src,
    int* __restrict__ curB, int2* __restrict__ tmp, int E, int NB)
{
    __shared__ int hist[512];
    __shared__ int basev[512];
    const int tid = threadIdx.x;
    const int base = blockIdx.x * 4096;
    for (int i = tid; i < NB; i += 256) hist[i] = 0;
    __syncthreads();
    int d[16];
#pragma unroll
    for (int k = 0; k < 16; ++k) {
        int e = base + k * 256 + tid;
        d[k] = (e < E) ? dst[e] : -1;
        if (d[k] >= 0) atomicAdd(&hist[d[k] >> 8], 1);
    }
    __syncthreads();
    for (int i = tid; i < NB; i += 256) {
        int c = hist[i];
        basev[i] = c > 0 ? atomicAdd(&curB[i], c) : 0;
        hist[i] = 0;
    }
    __syncthreads();
#pragma unroll
    for (int k = 0; k < 16; ++k) {
        int e = base + k * 256 + tid;
        if (d[k] >= 0) {
            int b = d[k] >> 8;
            int r = atomicAdd(&hist[b], 1);
            tmp[basev[b] + r] = make_int2(e | ((d[k] & 255) << 22), src[e]);
        }
    }
}

// ================= pass B: per-node offsets in LDS + scatter + write off[] =====
__global__ __launch_bounds__(256) void binB_kernel(
    const int2* __restrict__ tmp, const int* __restrict__ bucketOff,
    const uint4* __restrict__ eab4,
    int* __restrict__ off, int* __restrict__ srcarr, uint4* __restrict__ easrt,
    int N, int E, int NB)
{
    __shared__ int hist[256];
    __shared__ int ss[256];
    const int b = blockIdx.x;
    const int tid = threadIdx.x;
    const int node0 = b << 8;
    const int base = bucketOff[b];
    const int end = bucketOff[b + 1];
    const int S = end - base;

    hist[tid] = 0;
    __syncthreads();
    for (int j = tid; j < S; j += 256) {
        int2 rec = tmp[base + j];
        atomicAdd(&hist[((unsigned)rec.x) >> 22], 1);
    }
    __syncthreads();
    int v = hist[tid];
    ss[tid] = v;
    __syncthreads();
    for (int o = 1; o < 256; o <<= 1) {
        int val = (tid >= o) ? ss[tid - o] : 0;
        __syncthreads();
        ss[tid] += val;
        __syncthreads();
    }
    int excl = ss[tid] - v;
    int node = node0 + tid;
    if (node < N) off[node] = base + excl;
    if (b == NB - 1 && tid == 0) off[N] = E;
    hist[tid] = excl;     // reuse as cursor
    __syncthreads();
    for (int j = tid; j < S; j += 256) {
        int2 rec = tmp[base + j];
        int dloc = ((unsigned)rec.x) >> 22;
        int slot = base + atomicAdd(&hist[dloc], 1);
        srcarr[slot] = rec.y;
        easrt[slot] = eab4[rec.x & 0x3FFFFF];   // one-time random ea gather
    }
}

// ================= conv1 gather-aggregate (f16 gathers, sequential ea) =================
__global__ __launch_bounds__(256) void agg1_kernel(
    const float* __restrict__ x, const unsigned* __restrict__ xh,
    const uint4* __restrict__ easrt,
    const float* __restrict__ We, const float* __restrict__ be,
    const int* __restrict__ off, const int* __restrict__ srcarr,
    unsigned* __restrict__ aggh, int N)
{
    int wave = (blockIdx.x * 256 + threadIdx.x) >> 6;
    if (wave >= N) return;
    int lane = threadIdx.x & 63;
    int fp = lane & 15, eg = lane >> 4;
    int j0 = fp * 2;
    f16x2 w2[F_EDGE];
#pragma unroll
    for (int k = 0; k < F_EDGE; ++k)
        w2[k] = u2h(packh2(We[k * F_NODE + j0], We[k * F_NODE + j0 + 1]));
    f16x2 bias2 = u2h(packh2(be[j0], be[j0 + 1]));
    f16x2 zero2 = u2h(0u);
    int i0 = __builtin_amdgcn_readfirstlane(off[wave]);
    int i1 = __builtin_amdgcn_readfirstlane(off[wave + 1]);
    float acc0 = 0.f, acc1 = 0.f;
    for (int i = i0; i < i1; i += 4) {
        int ii = i + eg;
        if (ii < i1) {
            int s = srcarr[ii];
            f16x8 ev = frag_from(easrt[ii]);
            f16x2 m = bias2 + u2h(xh[(size_t)s * 16 + fp]);
#pragma unroll
            for (int k = 0; k < F_EDGE; ++k)
                m = duph(ev, k) * w2[k] + m;
            m = __builtin_elementwise_max(m, zero2);
            acc0 += (float)m.x;
            acc1 += (float)m.y;
        }
    }
    acc0 += __shfl_xor(acc0, 16, 64);
    acc0 += __shfl_xor(acc0, 32, 64);
    acc1 += __shfl_xor(acc1, 16, 64);
    acc1 += __shfl_xor(acc1, 32, 64);
    if (eg == 0) {
        float2 xo = *(const float2*)&x[(size_t)wave * F_NODE + j0];
        aggh[(size_t)wave * 16 + fp] = packh2(xo.x + acc0, xo.y + acc1);
    }
}

// ================= conv2 gather-aggregate (fp8 gathers, unroll 8) =================
__global__ __launch_bounds__(256) void agg2_kernel(
    const unsigned* __restrict__ hh, const unsigned short* __restrict__ h8,
    const uint4* __restrict__ easrt,
    const float* __restrict__ We, const float* __restrict__ be,
    const int* __restrict__ off, const int* __restrict__ srcarr,
    unsigned* __restrict__ aggh, int N)
{
    int wave = (blockIdx.x * 256 + threadIdx.x) >> 6;
    if (wave >= N) return;
    int lane = threadIdx.x & 63;
    int j0 = lane * 2;
    f16x2 w2[F_EDGE];
#pragma unroll
    for (int k = 0; k < F_EDGE; ++k)
        w2[k] = u2h(packh2(We[k * HID + j0], We[k * HID + j0 + 1]));
    f16x2 bias2 = u2h(packh2(be[j0], be[j0 + 1]));
    f16x2 zero2 = u2h(0u);
    int i0 = __builtin_amdgcn_readfirstlane(off[wave]);
    int i1 = __builtin_amdgcn_readfirstlane(off[wave + 1]);
    float acc0 = 0.f, acc1 = 0.f;
    int i = i0;
    for (; i + 7 < i1; i += 8) {
        int s[8];
        unsigned short u[8];
        f16x8 ev[8];
#pragma unroll
        for (int k = 0; k < 8; ++k) s[k] = srcarr[i + k];
#pragma unroll
        for (int k = 0; k < 8; ++k) u[k] = h8[(size_t)s[k] * 64 + lane];
#pragma unroll
        for (int k = 0; k < 8; ++k) ev[k] = frag_from(easrt[i + k]);
        f16x2 m[8];
#pragma unroll
        for (int k = 0; k < 8; ++k) {
            f32x2 f = __builtin_amdgcn_cvt_pk_f32_fp8((int)u[k], false);
            m[k] = bias2 + __builtin_amdgcn_cvt_pkrtz(f.x, f.y);
        }
#pragma unroll
        for (int kk = 0; kk < F_EDGE; ++kk) {
#pragma unroll
            for (int k = 0; k < 8; ++k)
                m[k] = duph(ev[k], kk) * w2[kk] + m[k];
        }
        f16x2 sm = __builtin_elementwise_max(m[0], zero2);
#pragma unroll
        for (int k = 1; k < 8; ++k) sm = sm + __builtin_elementwise_max(m[k], zero2);
        acc0 += (float)sm.x;
        acc1 += (float)sm.y;
    }
    for (; i < i1; ++i) {
        int s0 = srcarr[i];
        f16x8 e0 = frag_from(easrt[i]);
        f32x2 f = __builtin_amdgcn_cvt_pk_f32_fp8((int)h8[(size_t)s0 * 64 + lane], false);
        f16x2 m0 = bias2 + __builtin_amdgcn_cvt_pkrtz(f.x, f.y);
#pragma unroll
        for (int k = 0; k < F_EDGE; ++k)
            m0 = duph(e0, k) * w2[k] + m0;
        m0 = __builtin_elementwise_max(m0, zero2);
        acc0 += (float)m0.x;
        acc1 += (float)m0.y;
    }
    f16x2 self = u2h(hh[(size_t)wave * 64 + lane]);
    aggh[(size_t)wave * 64 + lane] = packh2((float)self.x + acc0, (float)self.y + acc1);
}

// ================= fused 2-layer node MLP via f16 MFMA =================
__device__ __forceinline__ void put_tile_elu_h(unsigned short* t, f32x4 v, int rbase, int c, int stride) {
#pragma unroll
    for (int j = 0; j < 4; ++j)
        t[(rbase + j) * stride + c] = f2h_bits(elu_f(v[j]));
}
__device__ __forceinline__ void put_tile_relu_h(unsigned short* t, f32x4 v, int rbase, int c, int stride) {
#pragma unroll
    for (int j = 0; j < 4; ++j)
        t[(rbase + j) * stride + c] = f2h_bits(fmaxf(v[j], 0.f));
}

template <int K, bool POOL, bool DUP8>
__global__ __launch_bounds__(256) void mlp_mfma_kernel(
    const uint4* __restrict__ inb,
    const uint4* __restrict__ WaP, const float* __restrict__ ba,
    const uint4* __restrict__ WbP, const float* __restrict__ bb,
    uint4* __restrict__ outb, unsigned* __restrict__ out8,
    const int* __restrict__ batch, float* __restrict__ hg,
    int nrows)
{
    constexpr int KS_A = K / 32;
    constexpr int SA = K + 8;
    constexpr int ST = HID + 8;
    constexpr int STF = HID + 4;
    __shared__ __align__(16) unsigned short a_s[32 * SA];
    __shared__ __align__(16) unsigned short t_s[32 * ST];
    __shared__ float p_s[POOL ? 32 * STF : 1];
    __shared__ int batch_s[POOL ? 32 : 1];

    const int tid = threadIdx.x;
    const int row0 = blockIdx.x * 32;

    constexpr int Q = K / 8;
    for (int idx = tid; idx < 32 * Q; idx += 256) {
        int r = idx / Q, q = idx % Q;
        uint4 v = make_uint4(0, 0, 0, 0);
        if (row0 + r < nrows) v = inb[(size_t)(row0 + r) * Q + q];
        *(uint4*)&a_s[r * SA + q * 8] = v;
    }
    if (POOL && tid < 32)
        batch_s[tid] = (row0 + tid < nrows) ? batch[row0 + tid] : -1;
    __syncthreads();

    const int lane = tid & 63;
    const int w = tid >> 6;
    const int rb = w >> 1;
    const int cg = (w & 1) * 4;
    const int cf = lane & 15;
    const int g = lane >> 4;
    const int arow = rb * 16 + cf;

    f32x4 acc0, acc1, acc2, acc3;
    {
        float c0 = ba[(cg + 0) * 16 + cf], c1 = ba[(cg + 1) * 16 + cf];
        float c2 = ba[(cg + 2) * 16 + cf], c3 = ba[(cg + 3) * 16 + cf];
        acc0 = (f32x4){c0, c0, c0, c0};
        acc1 = (f32x4){c1, c1, c1, c1};
        acc2 = (f32x4){c2, c2, c2, c2};
        acc3 = (f32x4){c3, c3, c3, c3};
    }
#pragma unroll
    for (int ks = 0; ks < KS_A; ++ks) {
        f16x8 a = *(const f16x8*)&a_s[arow * SA + ks * 32 + g * 8];
        acc0 = __builtin_amdgcn_mfma_f32_16x16x32_f16(a, frag_from(WaP[((cg + 0) * KS_A + ks) * 64 + lane]), acc0, 0, 0, 0);
        acc1 = __builtin_amdgcn_mfma_f32_16x16x32_f16(a, frag_from(WaP[((cg + 1) * KS_A + ks) * 64 + lane]), acc1, 0, 0, 0);
        acc2 = __builtin_amdgcn_mfma_f32_16x16x32_f16(a, frag_from(WaP[((cg + 2) * KS_A + ks) * 64 + lane]), acc2, 0, 0, 0);
        acc3 = __builtin_amdgcn_mfma_f32_16x16x32_f16(a, frag_from(WaP[((cg + 3) * KS_A + ks) * 64 + lane]), acc3, 0, 0, 0);
    }
    {
        int rbase = rb * 16 + g * 4;
        put_tile_elu_h(t_s, acc0, rbase, (cg + 0) * 16 + cf, ST);
        put_tile_elu_h(t_s, acc1, rbase, (cg + 1) * 16 + cf, ST);
        put_tile_elu_h(t_s, acc2, rbase, (cg + 2) * 16 + cf, ST);
        put_tile_elu_h(t_s, acc3, rbase, (cg + 3) * 16 + cf, ST);
    }
    __syncthreads();

    {
        float c0 = bb[(cg + 0) * 16 + cf], c1 = bb[(cg + 1) * 16 + cf];
        float c2 = bb[(cg + 2) * 16 + cf], c3 = bb[(cg + 3) * 16 + cf];
        acc0 = (f32x4){c0, c0, c0, c0};
        acc1 = (f32x4){c1, c1, c1, c1};
        acc2 = (f32x4){c2, c2, c2, c2};
        acc3 = (f32x4){c3, c3, c3, c3};
    }
#pragma unroll
    for (int ks = 0; ks < 4; ++ks) {
        f16x8 a = *(const f16x8*)&t_s[arow * ST + ks * 32 + g * 8];
        acc0 = __builtin_amdgcn_mfma_f32_16x16x32_f16(a, frag_from(WbP[((cg + 0) * 4 + ks) * 64 + lane]), acc0, 0, 0, 0);
        acc1 = __builtin_amdgcn_mfma_f32_16x16x32_f16(a, frag_from(WbP[((cg + 1) * 4 + ks) * 64 + lane]), acc1, 0, 0, 0);
        acc2 = __builtin_amdgcn_mfma_f32_16x16x32_f16(a, frag_from(WbP[((cg + 2) * 4 + ks) * 64 + lane]), acc2, 0, 0, 0);
        acc3 = __builtin_amdgcn_mfma_f32_16x16x32_f16(a, frag_from(WbP[((cg + 3) * 4 + ks) * 64 + lane]), acc3, 0, 0, 0);
    }

    if (POOL) {
        int rbase = rb * 16 + g * 4;
#pragma unroll
        for (int j = 0; j < 4; ++j) {
            p_s[(rbase + j) * STF + (cg + 0) * 16 + cf] = elu_f(acc0[j]);
            p_s[(rbase + j) * STF + (cg + 1) * 16 + cf] = elu_f(acc1[j]);
            p_s[(rbase + j) * STF + (cg + 2) * 16 + cf] = elu_f(acc2[j]);
            p_s[(rbase + j) * STF + (cg + 3) * 16 + cf] = elu_f(acc3[j]);
        }
        __syncthreads();
        int f = tid & 127, grp = tid >> 7;
        float acc = 0.f;
        int cur = -1;
#pragma unroll 4
        for (int r = 0; r < 16; ++r) {
            int rr = grp * 16 + r;
            int b = batch_s[rr];
            if (b >= 0) {
                if (b != cur) {
                    if (cur >= 0) atomicAdd(&hg[(size_t)cur * HID + f], acc);
                    acc = 0.f;
                    cur = b;
                }
                acc += p_s[rr * STF + f];
            }
        }
        if (cur >= 0) atomicAdd(&hg[(size_t)cur * HID + f], acc);
    } else {
        __syncthreads();
        int rbase = rb * 16 + g * 4;
        put_tile_elu_h(t_s, acc0, rbase, (cg + 0) * 16 + cf, ST);
        put_tile_elu_h(t_s, acc1, rbase, (cg + 1) * 16 + cf, ST);
        put_tile_elu_h(t_s, acc2, rbase, (cg + 2) * 16 + cf, ST);
        put_tile_elu_h(t_s, acc3, rbase, (cg + 3) * 16 + cf, ST);
        __syncthreads();
        for (int idx = tid; idx < 32 * 16; idx += 256) {
            int r = idx >> 4, q = idx & 15;
            if (row0 + r < nrows)
                outb[(size_t)(row0 + r) * 16 + q] = *(const uint4*)&t_s[r * ST + q * 8];
        }
        if (DUP8) {
            for (int idx = tid; idx < 32 * 32; idx += 256) {
                int r = idx >> 5, q = idx & 31;
                if (row0 + r < nrows) {
                    float f0 = hbits2f(t_s[r * ST + q * 4 + 0]);
                    float f1 = hbits2f(t_s[r * ST + q * 4 + 1]);
                    float f2 = hbits2f(t_s[r * ST + q * 4 + 2]);
                    float f3 = hbits2f(t_s[r * ST + q * 4 + 3]);
                    int u = __builtin_amdgcn_cvt_pk_fp8_f32(f0, f1, 0, false);
                    u = __builtin_amdgcn_cvt_pk_fp8_f32(f2, f3, u, true);
                    out8[(size_t)(row0 + r) * 32 + q] = (unsigned)u;
                }
            }
        }
    }
}

// ================= head via MFMA =================
__global__ __launch_bounds__(256) void head_mfma_kernel(
    const float* __restrict__ hg,
    const uint4* __restrict__ Wl1P, const float* __restrict__ bl1,
    const uint4* __restrict__ Wl2P, const float* __restrict__ bl2,
    float* __restrict__ out, int G)
{
    constexpr int ST = HID + 8;
    __shared__ __align__(16) unsigned short a_s[32 * ST];
    __shared__ __align__(16) unsigned short t_s[32 * ST];

    const int tid = threadIdx.x;
    const int row0 = blockIdx.x * 32;

    for (int idx = tid; idx < 32 * HID; idx += 256) {
        int r = idx >> 7, c = idx & 127;
        float v = (row0 + r < G) ? hg[(size_t)(row0 + r) * HID + c] : 0.f;
        a_s[r * ST + c] = f2h_bits(v);
    }
    __syncthreads();

    const int lane = tid & 63;
    const int w = tid >> 6;
    const int rb = w >> 1;
    const int cg = (w & 1) * 4;
    const int cf = lane & 15;
    const int g = lane >> 4;
    const int arow = rb * 16 + cf;

    f32x4 acc0, acc1, acc2, acc3;
    {
        float c0 = bl1[(cg + 0) * 16 + cf], c1 = bl1[(cg + 1) * 16 + cf];
        float c2 = bl1[(cg + 2) * 16 + cf], c3 = bl1[(cg + 3) * 16 + cf];
        acc0 = (f32x4){c0, c0, c0, c0};
        acc1 = (f32x4){c1, c1, c1, c1};
        acc2 = (f32x4){c2, c2, c2, c2};
        acc3 = (f32x4){c3, c3, c3, c3};
    }
#pragma unroll
    for (int ks = 0; ks < 4; ++ks) {
        f16x8 a = *(const f16x8*)&a_s[arow * ST + ks * 32 + g * 8];
        acc0 = __builtin_amdgcn_mfma_f32_16x16x32_f16(a, frag_from(Wl1P[((cg + 0) * 4 + ks) * 64 + lane]), acc0, 0, 0, 0);
        acc1 = __builtin_amdgcn_mfma_f32_16x16x32_f16(a, frag_from(Wl1P[((cg + 1) * 4 + ks) * 64 + lane]), acc1, 0, 0, 0);
        acc2 = __builtin_amdgcn_mfma_f32_16x16x32_f16(a, frag_from(Wl1P[((cg + 2) * 4 + ks) * 64 + lane]), acc2, 0, 0, 0);
        acc3 = __builtin_amdgcn_mfma_f32_16x16x32_f16(a, frag_from(Wl1P[((cg + 3) * 4 + ks) * 64 + lane]), acc3, 0, 0, 0);
    }
    {
        int rbase = rb * 16 + g * 4;
        put_tile_relu_h(t_s, acc0, rbase, (cg + 0) * 16 + cf, ST);
        put_tile_relu_h(t_s, acc1, rbase, (cg + 1) * 16 + cf, ST);
        put_tile_relu_h(t_s, acc2, rbase, (cg + 2) * 16 + cf, ST);
        put_tile_relu_h(t_s, acc3, rbase, (cg + 3) * 16 + cf, ST);
    }
    __syncthreads();

    if ((w & 1) == 0) {
        float c0 = cf < 12 ? bl2[cf] : 0.f;
        f32x4 acc = (f32x4){c0, c0, c0, c0};
#pragma unroll
        for (int ks = 0; ks < 4; ++ks) {
            f16x8 a = *(const f16x8*)&t_s[arow * ST + ks * 32 + g * 8];
            acc = __builtin_amdgcn_mfma_f32_16x16x32_f16(a, frag_from(Wl2P[ks * 64 + lane]), acc, 0, 0, 0);
        }
        if (cf < 12) {
            int rbase = rb * 16 + g * 4;
#pragma unroll
            for (int j = 0; j < 4; ++j) {
                int row = row0 + rbase + j;
                if (row < G) out[(size_t)row * 12 + cf] = acc[j];
            }
        }
    }
}

extern "C" void kernel_launch(void* const* d_in, const int* in_sizes, int n_in,
                              void* d_out, int out_size, void* d_ws, size_t ws_size,
                              hipStream_t stream)
{
    const float* x    = (const float*)d_in[0];
    const int*   ei   = (const int*)d_in[1];
    const float* ea   = (const float*)d_in[2];
    const int*   batch = (const int*)d_in[3];
    const float* We1 = (const float*)d_in[4];
    const float* be1 = (const float*)d_in[5];
    const float* W1a = (const float*)d_in[6];
    const float* b1a = (const float*)d_in[7];
    const float* W1b = (const float*)d_in[8];
    const float* b1b = (const float*)d_in[9];
    const float* We2 = (const float*)d_in[10];
    const float* be2 = (const float*)d_in[11];
    const float* W2a = (const float*)d_in[12];
    const float* b2a = (const float*)d_in[13];
    const float* W2b = (const float*)d_in[14];
    const float* b2b = (const float*)d_in[15];
    const float* Wl1 = (const float*)d_in[16];
    const float* bl1 = (const float*)d_in[17];
    const float* Wl2 = (const float*)d_in[18];
    const float* bl2 = (const float*)d_in[19];
    float* out = (float*)d_out;

    const int N = in_sizes[0] / F_NODE;
    const int E = in_sizes[1] / 2;
    const int G = out_size / 12;
    const int NB = (N + 255) >> 8;

    const int* srcp = ei;
    const int* dstp = ei + E;

    // ---- workspace layout (lifetime-based aliasing) ----
    char* wsb = (char*)d_ws;
    auto alloc = [&](size_t bytes) -> char* {
        char* p = wsb;
        wsb += (bytes + 15) & ~(size_t)15;
        return p;
    };
    int* cbkt      = (int*)alloc(512 * 4);
    int* bucketOff = (int*)alloc(513 * 4);
    int* curB      = (int*)alloc(512 * 4);
    int* off       = (int*)alloc((size_t)(N + 1) * 4);
    int2* tmp      = (int2*)alloc((size_t)E * 8);          // dead after binB -> reused as h8
    unsigned short* h8 = (unsigned short*)tmp;             // N*128 fp8 bytes <= E*8
    int* srcarr    = (int*)alloc((size_t)E * 4);
    uint4* easrt   = (uint4*)alloc((size_t)E * 16);
    unsigned* xh   = (unsigned*)alloc((size_t)N * 16 * 4);
    unsigned* eab  = (unsigned*)alloc((size_t)E * 4 * 4);  // dead after binB -> reused as agg2h
    unsigned* agg2h = eab;
    unsigned* agg1h = (unsigned*)alloc((size_t)N * 16 * 4);
    unsigned* h1h   = (unsigned*)alloc((size_t)N * 64 * 4);
    float* hg  = (float*)alloc((size_t)G * HID * 4);
    uint4* P1a = (uint4*)alloc(512 * 16);
    uint4* P1b = (uint4*)alloc(2048 * 16);
    uint4* P2a = (uint4*)alloc(2048 * 16);
    uint4* P2b = (uint4*)alloc(2048 * 16);
    uint4* P3a = (uint4*)alloc(2048 * 16);
    uint4* P3b = (uint4*)alloc(256 * 16);

    (void)hipMemsetAsync(cbkt, 0, 512 * sizeof(int), stream);
    (void)hipMemsetAsync(hg, 0, (size_t)G * HID * sizeof(float), stream);

    // ---- prep: casts + wpack + coarse hist ----
    hipLaunchKernelGGL(prep_kernel, dim3(2048), dim3(256), 0, stream,
                       x, ea, dstp, (uint4*)xh, (uint4*)eab, W1a, W1b, W2a, W2b, Wl1, Wl2,
                       P1a, P1b, P2a, P2b, P3a, P3b, cbkt, N * 16, E * 4, E, NB);
    hipLaunchKernelGGL(scanB_kernel, dim3(1), dim3(256), 0, stream, cbkt, bucketOff, curB, NB, E);
    hipLaunchKernelGGL(binA_kernel, dim3((E + 4095) / 4096), dim3(256), 0, stream,
                       dstp, srcp, curB, tmp, E, NB);
    hipLaunchKernelGGL(binB_kernel, dim3(NB), dim3(256), 0, stream,
                       tmp, bucketOff, (const uint4*)eab, off, srcarr, easrt, N, E, NB);

    // ---- conv1 ----
    hipLaunchKernelGGL(agg1_kernel, dim3((N + 3) / 4), dim3(256), 0, stream,
                       x, xh, easrt, We1, be1, off, srcarr, agg1h, N);
    hipLaunchKernelGGL((mlp_mfma_kernel<F_NODE, false, true>), dim3((N + 31) / 32), dim3(256), 0, stream,
                       (const uint4*)agg1h, P1a, b1a, P1b, b1b, (uint4*)h1h, (unsigned*)h8,
                       (const int*)nullptr, (float*)nullptr, N);

    // ---- conv2 ----
    hipLaunchKernelGGL(agg2_kernel, dim3((N + 3) / 4), dim3(256), 0, stream,
                       h1h, h8, easrt, We2, be2, off, srcarr, agg2h, N);
    hipLaunchKernelGGL((mlp_mfma_kernel<HID, true, false>), dim3((N + 31) / 32), dim3(256), 0, stream,
                       (const uint4*)agg2h, P2a, b2a, P2b, b2b, (uint4*)nullptr, (unsigned*)nullptr,
                       batch, hg, N);

    // ---- head (MFMA) ----
    hipLaunchKernelGGL(head_mfma_kernel, dim3((G + 31) / 32), dim3(256), 0, stream,
                       hg, P3a, bl1, P3b, bl2, out, G);
}